// Round 1
// baseline (120.705 us; speedup 1.0000x reference)
//
#include <hip/hip_runtime.h>

// MCPBRNN_constant_OutLoss: closed-form evaluation.
// Key insight: the length-(B*T) linear recurrence c[k] = f*c[k-1] + u[k] has a
// constant coefficient f <= e/(2+e) ~ 0.576, so f^64 < 5e-16 — every sampled
// carry c0[i] = c[4i+2] equals a 64-term windowed sum to full f32 precision.

#define SPIN 1000
#define TRAIN 500000
#define NPART 256
#define WIN 64

__global__ void reduce_partial_k(const float* __restrict__ y, int B,
                                 double* __restrict__ part) {
  int hi = TRAIN < B ? TRAIN : B;
  float s = 0.f, s2 = 0.f;
  for (int i = SPIN + blockIdx.x * blockDim.x + threadIdx.x; i < hi;
       i += gridDim.x * blockDim.x) {
    float v = y[i];
    s += v;
    s2 += v * v;
  }
  for (int off = 32; off; off >>= 1) {
    s += __shfl_down(s, off, 64);
    s2 += __shfl_down(s2, off, 64);
  }
  __shared__ float ls[4], ls2[4];
  int t = threadIdx.x;
  if ((t & 63) == 0) { ls[t >> 6] = s; ls2[t >> 6] = s2; }
  __syncthreads();
  if (t == 0) {
    double S = 0, S2 = 0;
    for (int j = 0; j < 4; ++j) { S += ls[j]; S2 += ls2[j]; }
    part[2 * blockIdx.x] = S;
    part[2 * blockIdx.x + 1] = S2;
  }
}

__global__ void finalize_scalars_k(const double* __restrict__ part,
                                   const float* __restrict__ wom,
                                   const float* __restrict__ wlm,
                                   const float* __restrict__ wfm, int B,
                                   float* __restrict__ sc) {
  __shared__ double ss[NPART], ss2[NPART];
  int t = threadIdx.x;
  ss[t] = part[2 * t];
  ss2[t] = part[2 * t + 1];
  __syncthreads();
  for (int off = NPART / 2; off; off >>= 1) {
    if (t < off) { ss[t] += ss[t + off]; ss2[t] += ss2[t + off]; }
    __syncthreads();
  }
  if (t == 0) {
    int hi = TRAIN < B ? TRAIN : B;
    double n = (double)(hi - SPIN);
    double S = ss[0], S2 = ss2[0];
    double var = (S2 - S * S / n) / (n - 1.0);
    float sd = (float)sqrt(var > 0.0 ? var : 0.0);
    float eo = expf(wom[0]), el = expf(wlm[0]), ef = expf(wfm[0]);
    float denom = eo + el + ef;
    float oo = eo / denom, ol = el / denom;
    float f = 1.f - oo - ol;  // reference computes f this exact way
    sc[0] = oo; sc[1] = ol; sc[2] = f; sc[3] = sd;
  }
}

__global__ void __launch_bounds__(256)
main_out_k(const float* __restrict__ x, const int* __restrict__ tl_p,
           const float* __restrict__ sc, float* __restrict__ out, int B) {
  __shared__ float u[1088];  // max needed: 255*4 + WIN = 1084
  const int tl = tl_p[0];
  const float oo = sc[0], ol = sc[1], f = sc[2], sd = sc[3];

  const long b0 = (long)blockIdx.x * 256;
  const long i0 = b0 - tl;
  long k_last = i0 * 4 + 2 + 255 * 4;       // k_end of last thread in block
  long k_lo = i0 * 4 + 2 - (WIN - 1);
  if (k_lo < 0) k_lo = 0;
  const long kmax = ((long)B - tl) * 4;     // exclusive valid-u bound
  long count = k_last - k_lo + 1;
  if (k_last < 0) count = 0;
  if (count > 1088) count = 1088;

  const int t = threadIdx.x;
  for (long idx = t; idx < count; idx += 256) {
    long k = k_lo + idx;
    float v = 0.f;
    if (k < kmax) v = x[(long)tl * 8 + 2 * k];  // u[k] = x[tl*8 + 2k]
    u[idx] = v;
  }
  __syncthreads();

  const long b = b0 + t;
  if (b >= B) return;
  float c0 = 0.f;
  const bool valid = (b >= tl);
  if (valid) {
    long i = b - tl;
    long ke = i * 4 + 2;
    long ks = ke - (WIN - 1);
    if (ks < 0) ks = 0;
    for (long k = ks; k <= ke; ++k) c0 = fmaf(f, c0, u[k - k_lo]);
  }
  const float h = oo * c0;
  const float l = ol * c0;
  const long Bl = B;
  out[b] = h;                         // h_n
  out[Bl + b] = c0;                   // c_n
  out[2 * Bl + b] = l;                // l_n
  out[3 * Bl + b] = 0.f;              // bp_n
  out[4 * Bl + b] = 0.f;              // Gate_ib
  out[5 * Bl + b] = valid ? oo : 0.f; // Gate_oo
  out[6 * Bl + b] = valid ? ol : 0.f; // Gate_ol
  out[7 * Bl + b] = valid ? f : 0.f;  // Gate_f
  const float sdm = valid ? sd : 0.f;
  reinterpret_cast<float2*>(out + 8 * Bl)[b] = make_float2(h, sdm);  // h_nout
  out[10 * Bl + b] = sdm;             // obs_std
}

extern "C" void kernel_launch(void* const* d_in, const int* in_sizes, int n_in,
                              void* d_out, int out_size, void* d_ws,
                              size_t ws_size, hipStream_t stream) {
  const float* x = (const float*)d_in[0];
  const float* y_obs = (const float*)d_in[1];
  const float* wom = (const float*)d_in[2];
  const float* wlm = (const float*)d_in[3];
  const float* wfm = (const float*)d_in[4];
  // d_in[5] = epoch (unused)
  const int* tl = (const int*)d_in[6];
  float* out = (float*)d_out;
  const int B = in_sizes[1];  // y_obs is (B,1)

  float* sc = (float*)d_ws;                          // 4 floats
  double* part = (double*)((char*)d_ws + 64);        // NPART double2

  reduce_partial_k<<<NPART, 256, 0, stream>>>(y_obs, B, part);
  finalize_scalars_k<<<1, NPART, 0, stream>>>(part, wom, wlm, wfm, B, sc);
  const int grid = (B + 255) / 256;
  main_out_k<<<grid, 256, 0, stream>>>(x, tl, sc, out, B);
}

// Round 2
// 112.804 us; speedup vs baseline: 1.0700x; 1.0700x over previous
//
#include <hip/hip_runtime.h>

// MCPBRNN_constant_OutLoss: closed-form evaluation.
// c[k] = f*c[k-1] + u[k] with constant f <= e/(2+e) ~ 0.576 => f^64 < 5e-16,
// so each sampled carry c0[i] = c[4i+2] is a 64-term windowed sum to full f32
// precision. Window evaluated as 1 partial quad + 15 full quads + 1 partial
// quad using conflict-free ds_read_b128 (lane stride 16B).

#define SPIN 1000
#define TRAIN 500000
#define NPART 256

// Kernel 1: per-block partial (sum, sumsq) of y[SPIN:min(TRAIN,B)) as doubles.
__global__ void __launch_bounds__(256)
reduce_partial_k(const float* __restrict__ y, int B, double* __restrict__ part) {
  const int hi = TRAIN < B ? TRAIN : B;
  const int q0 = SPIN / 4;          // SPIN % 4 == 0
  const int q1 = hi / 4;
  float s = 0.f, s2 = 0.f;
  const float4* y4 = reinterpret_cast<const float4*>(y);
  for (int q = q0 + blockIdx.x * 256 + threadIdx.x; q < q1; q += NPART * 256) {
    float4 v = y4[q];
    s += v.x + v.y + v.z + v.w;
    s2 += v.x * v.x + v.y * v.y + v.z * v.z + v.w * v.w;
  }
  if (blockIdx.x == 0 && threadIdx.x == 0) {  // tail (only if hi % 4 != 0)
    for (int i = q1 * 4; i < hi; ++i) { float v = y[i]; s += v; s2 += v * v; }
  }
  for (int off = 32; off; off >>= 1) {
    s += __shfl_down(s, off, 64);
    s2 += __shfl_down(s2, off, 64);
  }
  __shared__ float ls[4], ls2[4];
  const int t = threadIdx.x;
  if ((t & 63) == 0) { ls[t >> 6] = s; ls2[t >> 6] = s2; }
  __syncthreads();
  if (t == 0) {
    double S = 0, S2 = 0;
    for (int j = 0; j < 4; ++j) { S += ls[j]; S2 += ls2[j]; }
    part[2 * blockIdx.x] = S;
    part[2 * blockIdx.x + 1] = S2;
  }
}

// Kernel 2: everything else. Each block redundantly folds the 256 partials
// (4KB, L2-broadcast) into the scalars, stages 272 quads of u in LDS, and
// computes 256 outputs via 17 b128 reads/thread.
__global__ void __launch_bounds__(256)
main_out_k(const float* __restrict__ x, const double* __restrict__ part,
           const float* __restrict__ wom, const float* __restrict__ wlm,
           const float* __restrict__ wfm, const int* __restrict__ tl_p,
           float* __restrict__ out, int B) {
  __shared__ float u[1088];   // 272 quads
  __shared__ float scal[4];   // oo, ol, f, sd

  const int t = threadIdx.x;
  const int tl = tl_p[0];
  const int b0 = blockIdx.x * 256;
  const int i0 = b0 - tl;
  const int klo4 = 4 * (i0 - 16);      // first staged u-index (quad aligned, may be <0)
  const int X0 = tl * 8;

  // ---- stage u: pair p -> u[klo4+2p], u[klo4+2p+1] via one float4 (stride-2 x) ----
  for (int p = t; p < 544; p += 256) {
    int k = klo4 + 2 * p;              // even
    float2 w = make_float2(0.f, 0.f);
    if (k >= 0) {                      // high side proven in-range for all blocks
      float4 v = *reinterpret_cast<const float4*>(x + X0 + 2 * k);
      w = make_float2(v.x, v.z);       // u[k] = x[X0 + 2k]
    }
    *reinterpret_cast<float2*>(&u[2 * p]) = w;
  }

  // ---- wave 0: fold partials -> scalars ----
  if (t < 64) {
    double S = 0, S2 = 0;
    for (int j = t; j < NPART; j += 64) { S += part[2 * j]; S2 += part[2 * j + 1]; }
    for (int m = 32; m; m >>= 1) {
      S += __shfl_xor(S, m, 64);
      S2 += __shfl_xor(S2, m, 64);
    }
    if (t == 0) {
      const int hi = TRAIN < B ? TRAIN : B;
      double n = (double)(hi - SPIN);
      double var = (S2 - S * S / n) / (n - 1.0);
      float sd = (float)sqrt(var > 0.0 ? var : 0.0);
      float eo = expf(wom[0]), el = expf(wlm[0]), ef = expf(wfm[0]);
      float denom = eo + el + ef;
      float oo = eo / denom, ol = el / denom;
      scal[0] = oo; scal[1] = ol; scal[2] = 1.f - oo - ol; scal[3] = sd;
    }
  }
  __syncthreads();

  const int b = b0 + t;
  if (b >= B) return;
  const float oo = scal[0], ol = scal[1], f = scal[2], sd = scal[3];
  const float f2 = f * f, f3 = f2 * f, f4 = f2 * f2;

  // ---- windowed recurrence: local quad index for thread t is t+m, m=0..16 ----
  const float4* uq = reinterpret_cast<const float4*>(u);
  float c = uq[t].w;                   // j=63 term: u[ke-63]
#pragma unroll
  for (int m = 1; m <= 15; ++m) {
    float4 q = uq[t + m];
    float w = fmaf(fmaf(fmaf(q.x, f, q.y), f, q.z), f, q.w);
    c = fmaf(f4, c, w);
  }
  float4 qf = uq[t + 16];
  c = fmaf(f3, c, fmaf(fmaf(qf.x, f, qf.y), f, qf.z));

  const bool valid = (b >= tl);
  if (!valid) c = 0.f;
  const float h = oo * c;
  const float l = ol * c;
  const int Bl = B;
  out[b] = h;                              // h_n
  out[Bl + b] = c;                         // c_n
  out[2 * Bl + b] = l;                     // l_n
  out[3 * Bl + b] = 0.f;                   // bp_n
  out[4 * Bl + b] = 0.f;                   // Gate_ib
  out[5 * Bl + b] = valid ? oo : 0.f;      // Gate_oo
  out[6 * Bl + b] = valid ? ol : 0.f;      // Gate_ol
  out[7 * Bl + b] = valid ? f : 0.f;       // Gate_f
  const float sdm = valid ? sd : 0.f;
  reinterpret_cast<float2*>(out + 8 * Bl)[b] = make_float2(h, sdm);  // h_nout
  out[10 * Bl + b] = sdm;                  // obs_std
}

extern "C" void kernel_launch(void* const* d_in, const int* in_sizes, int n_in,
                              void* d_out, int out_size, void* d_ws,
                              size_t ws_size, hipStream_t stream) {
  const float* x = (const float*)d_in[0];
  const float* y_obs = (const float*)d_in[1];
  const float* wom = (const float*)d_in[2];
  const float* wlm = (const float*)d_in[3];
  const float* wfm = (const float*)d_in[4];
  // d_in[5] = epoch (unused)
  const int* tl = (const int*)d_in[6];
  float* out = (float*)d_out;
  const int B = in_sizes[1];  // y_obs is (B,1)

  double* part = (double*)d_ws;  // NPART double2

  reduce_partial_k<<<NPART, 256, 0, stream>>>(y_obs, B, part);
  const int grid = (B + 255) / 256;
  main_out_k<<<grid, 256, 0, stream>>>(x, part, wom, wlm, wfm, tl, out, B);
}